// Round 8
// baseline (541.533 us; speedup 1.0000x reference)
//
#include <hip/hip_runtime.h>

typedef _Float16 half8 __attribute__((ext_vector_type(8)));
typedef _Float16 half4 __attribute__((ext_vector_type(4)));
typedef __fp16   pk2   __attribute__((ext_vector_type(2)));
typedef float    f32x4 __attribute__((ext_vector_type(4)));

#define GLOBAL_AS __attribute__((address_space(1)))
#define LDS_AS    __attribute__((address_space(3)))

static constexpr int Bb = 32;
static constexpr int Nn = 2048;
static constexpr int Dd = 1024;
static constexpr int M  = Bb * Nn;   // 65536 rows of the big GEMM

// ---------------------------------------------------------------------------
// B layout (prep_w1 -> gemm8): chunk format staged linearly by
// global_load_lds; bank swizzle pre-baked into the GLOBAL image.
// A: read f32 from `encoded`, reg-staged in TWO half-tile groups that REUSE
// the same 16 aSt VGPRs (arch budget is 256-total minus 128 acc AGPRs = 128;
// r6/r7's aSt[8]=32 pushed arch demand to ~155 -> 14 MB/dispatch scratch).
// A LDS image: half4 unit (row,kc) at row*16 + (kc ^ ((row&7)*2)) -- write
// side conflict-free (measured 0), read side 2-way (free).
// ---------------------------------------------------------------------------

// Kernel 1a: pack W1 (f32 [d][e]) -> swizzled f16 chunks.
__global__ void prep_w1(const float* __restrict__ W1, _Float16* __restrict__ W1TT) {
    int g = blockIdx.x * 256 + threadIdx.x;   // 131072 half8 units
    int chunk = g >> 10;                      // et*32 + t*2 + h
    int u = g & 1023;
    int q = u >> 7, sc = u & 127;
    int cl = sc ^ (2 * (q & 3));
    int et = chunk >> 5, t = (chunk >> 1) & 15, h = chunk & 1;
    int e  = et * 256 + h * 128 + cl;
    int k0 = t * 64 + q * 8;
    half8 hh;
#pragma unroll
    for (int j = 0; j < 8; ++j)
        hh[j] = (_Float16)W1[(size_t)(k0 + j) * Dd + e];
    *(half8*)(W1TT + (size_t)g * 8) = hh;
}

// ---------------------------------------------------------------------------
// Kernel 2: dec[b][e] = decoder_state[b] @ W2   (32x1024)
// ---------------------------------------------------------------------------
__global__ void dec_kernel(const float* __restrict__ ds, const float* __restrict__ W2,
                           float* __restrict__ dec) {
    __shared__ float part[4][64];
    int b = blockIdx.x, ech = blockIdx.y;
    int tid = threadIdx.x;
    int e = ech * 64 + (tid & 63);
    int dc = tid >> 6;
    float acc = 0.f;
#pragma unroll 4
    for (int d = dc * 256; d < dc * 256 + 256; ++d)
        acc += ds[b * Dd + d] * W2[(size_t)d * Dd + e];
    part[dc][tid & 63] = acc;
    __syncthreads();
    if (tid < 64)
        dec[b * Dd + e] = part[0][tid] + part[1][tid] + part[2][tid] + part[3][tid];
}

// ---------------------------------------------------------------------------
// Kernel 3: 256x256 tile, 8 waves, fused f32->f16 A-staging, register-lean.
// Per K-tile: issue 4 A-lo dwordx4 + 4 B global_load_lds; ds_read + counted
// lgkm quadrant overlap (q1,q2); VM(4)->write A-lo; REISSUE same aSt regs for
// A-hi; q3,q4 over the hi flight; VM(0)->write A-hi; LGKM(0); BAR.
// aSt shrinks 32->16 VGPR => arch demand ~110 < 128 cap (256 unified - 128
// acc AGPRs) => no scratch spill (r6/r7's 14 MB WRITE_SIZE).
// ---------------------------------------------------------------------------
#define BAR     asm volatile("s_barrier" ::: "memory")
#define LGKM(n) asm volatile("s_waitcnt lgkmcnt(" #n ")" ::: "memory")
#define VM(n)   asm volatile("s_waitcnt vmcnt(" #n ")" ::: "memory")
#define PRIO1   __builtin_amdgcn_s_setprio(1)
#define PRIO0   __builtin_amdgcn_s_setprio(0)

// A image: half4 unit (row,kc) -> halfword addr (row*16 + (kc ^ ((row&7)*2)))*4
#define RD_A(dst, base) do { _Pragma("unroll") \
  for (int ks = 0; ks < 2; ++ks) { \
    _Pragma("unroll") for (int m2 = 0; m2 < 4; ++m2) { \
      const int row_ = m2 * 32 + rA; \
      const int kc0_ = (ks * 4 + qq) * 2; \
      dst[m2][ks] = *(const half8*)&lds[(base) + (row_ * 16 + (kc0_ ^ rxa)) * 4]; \
    } } } while (0)

#define RD_B(dst, base) do { _Pragma("unroll") \
  for (int ks = 0; ks < 2; ++ks) { const int qb = ((ks * 4 + qq) * 128) * 8; \
    _Pragma("unroll") for (int j2 = 0; j2 < 2; ++j2) \
      dst[j2][ks] = *(const half8*)&lds[(base) + qb + (j2 * 64 + rB) * 8]; } } while (0)

#define MFMAQ(A_, B_, ro, co) do { \
  _Pragma("unroll") for (int m2 = 0; m2 < 4; ++m2) \
  _Pragma("unroll") for (int j2 = 0; j2 < 2; ++j2) { \
    acc[(ro) + m2][(co) + j2] = __builtin_amdgcn_mfma_f32_16x16x32_f16( \
        A_[m2][0], B_[j2][0], acc[(ro) + m2][(co) + j2], 0, 0, 0); \
    acc[(ro) + m2][(co) + j2] = __builtin_amdgcn_mfma_f32_16x16x32_f16( \
        A_[m2][1], B_[j2][1], acc[(ro) + m2][(co) + j2], 0, 0, 0); } } while (0)

__global__ __launch_bounds__(512, 2) void gemm8(
    const float* __restrict__ encA, const _Float16* __restrict__ W1TT,
    const float* __restrict__ dec, const float* __restrict__ vt,
    float* __restrict__ u_part)          // [4][65536]
{
    extern __shared__ _Float16 lds[];    // 65536 halfs = 128 KB

    const int g  = blockIdx.x;                   // 0..1023
    const int wg = (g & 7) * 128 + (g >> 3);     // XCD-chunked swizzle (1024%8==0)
    const int et    = wg & 3;                    // 4 consecutive wg share mtile
    const int mtile = wg >> 2;                   //  -> A slab L2-shared per XCD

    const int tid  = threadIdx.x;
    const int lane = tid & 63, wid = tid >> 6;
    const int wr = wid >> 2, wc = wid & 3;
    const int qq = lane >> 4, l15 = lane & 15;
    const int l15s = l15 ^ (2 * qq);             // B read-side bank swizzle
    const int rA = wr * 16 + l15;                // A rows: plain (layout swizzles)
    const int rxa = (l15 & 7) * 2;               // A read XOR (row&7)*2
    const int rB = wc * 16 + l15s;

    f32x4 acc[8][4] = {};
    half8 a[4][2], b0[2][2], b1[2][2];
    f32x4 aSt[4];                                // SHARED by lo and hi groups

    // A staging geometry: within a 128-row half, instr p covers rows
    // p*32 + (tid>>4); lane covers cols l16*4..+4 (4 rows x 256 B per instr).
    const int arow0 = tid >> 4;                  // 0..31
    const int l16   = tid & 15;
    const float* agp = encA + (((size_t)(mtile * 256 + arow0)) << 10) + l16 * 4;

    const size_t bbase = (size_t)et * 32 * 8192;
    const int uoff = tid * 8;                    // per-thread 16B within chunk

    auto issueA = [&](int T, int h) {            // 4 loads: rows h*128 + p*32
        const float* gp = agp + T * 64 + ((size_t)h << 17);
#pragma unroll
        for (int p = 0; p < 4; ++p)
            aSt[p] = *(const f32x4*)(gp + ((size_t)p << 15));
    };
    auto writeA = [&](int Tn, int h) {           // 4 conflict-free ds_write_b64
        const int base = ((Tn & 1) << 14) + h * 8192;
#pragma unroll
        for (int p = 0; p < 4; ++p) {
            const int row = p * 32 + arow0;      // 0..127 within half
            pk2 c0 = __builtin_amdgcn_cvt_pkrtz(aSt[p][0], aSt[p][1]);
            pk2 c1 = __builtin_amdgcn_cvt_pkrtz(aSt[p][2], aSt[p][3]);
            half4 hh; hh[0] = c0[0]; hh[1] = c0[1]; hh[2] = c1[0]; hh[3] = c1[1];
            *(half4*)&lds[base + (row * 16 + (l16 ^ ((row & 7) * 2))) * 4] = hh;
        }
    };
    auto stB = [&](int T, int h) {
        const _Float16* gp = W1TT + bbase + ((size_t)(T * 2 + h) << 13) + uoff;
        _Float16* lp = lds + (32768 + (((T & 1) * 2 + h) << 13) + (wid << 9));
        __builtin_amdgcn_global_load_lds((const GLOBAL_AS void*)gp,
                                         (LDS_AS void*)lp, 16, 0, 0);
        __builtin_amdgcn_global_load_lds((const GLOBAL_AS void*)(gp + 4096),
                                         (LDS_AS void*)(lp + 4096), 16, 0, 0);
    };

    // LDS bases (halfword units): tile slot = T&1.
    // A: slot0 h0=0, h1=8192 ; slot1 h0=16384, h1=24576.  B: +32768 each.

    // prologue: stage tile 0 (A lo/hi via shared regs, B via global_load_lds)
    issueA(0, 0); stB(0, 0); stB(0, 1);
    VM(4);  writeA(0, 0);
    __builtin_amdgcn_sched_barrier(0);
    issueA(0, 1);
    VM(0);  writeA(0, 1);
    LGKM(0);
    BAR;

#pragma unroll 1
    for (int T = 0; T < 16; ++T) {
        const int As  = (T & 1) << 14;           // A slot base (halfwords)
        const int Bs2 = 32768 + ((T & 1) << 14); // B slot base
        const bool s = (T < 15);

        // staging for tile T+1: A-lo (4 dwordx4) + B (4 gload_lds) in flight
        if (s) { issueA(T + 1, 0); stB(T + 1, 0); stB(T + 1, 1); }

        // tile T compute with counted-lgkm quadrant overlap
        RD_A(a, As);                 // 8 ds_read_b128 (rows 0..127)
        RD_B(b0, Bs2);               // 4
        RD_B(b1, Bs2 + 8192);        // 4
        LGKM(4);                     // a + b0 resident (b1 draining)
        PRIO1; MFMAQ(a, b0, 0, 0); PRIO0;
        LGKM(0);                     // b1 resident
        PRIO1; MFMAQ(a, b1, 0, 2); PRIO0;
        RD_A(a, As + 8192);          // rows 128..255 (WAR on a: safe, q2 issued)
        if (s) {
            VM(4);                   // A-lo landed (B still in flight)
            writeA(T + 1, 0);        // 4 ds_write_b64 into the other slot
            __builtin_amdgcn_sched_barrier(0);   // pin: hi-issue after lo-write
            issueA(T + 1, 1);        // reuse aSt; lands under q3/q4
            LGKM(4);                 // 8 a-reads done (4 writes may remain)
        } else {
            LGKM(0);
        }
        PRIO1; MFMAQ(a, b0, 4, 0); MFMAQ(a, b1, 4, 2); PRIO0;

        VM(0);                       // B + A-hi landed
        if (s) writeA(T + 1, 1);
        LGKM(0);                     // ds_writes retired
        BAR;                         // slot T&1 free; T+1 readable
    }

    // ---- epilogue: tanh(c + dec) * vt, reduce over this block's 256 cols ----
    const int b = mtile >> 3;                    // 8 mtiles per batch row
    float vtv[4], dcv[4];
#pragma unroll
    for (int nf = 0; nf < 4; ++nf) {
        int e = et * 256 + (nf >> 1) * 128 + (nf & 1) * 64 + wc * 16 + l15;
        vtv[nf] = vt[e];
        dcv[nf] = dec[b * Dd + e];
    }
    float* usum = (float*)lds;   // [4 wc][256 rows]; all staging drained
#pragma unroll
    for (int hm = 0; hm < 8; ++hm) {
        const int h = hm >> 2, mq = hm & 3;
#pragma unroll
        for (int r = 0; r < 4; ++r) {
            float sv = 0.f;
#pragma unroll
            for (int nf = 0; nf < 4; ++nf) {
                float x  = acc[hm][nf][r] + dcv[nf];
                float ex = __expf(2.f * x);
                sv += (1.f - 2.f * __builtin_amdgcn_rcpf(ex + 1.f)) * vtv[nf];
            }
#pragma unroll
            for (int off = 1; off < 16; off <<= 1) sv += __shfl_xor(sv, off, 16);
            if (l15 == 0)
                usum[wc * 256 + h * 128 + mq * 32 + wr * 16 + qq * 4 + r] = sv;
        }
    }
    __syncthreads();
    if (tid < 256) {
        float v = usum[tid] + usum[256 + tid] + usum[512 + tid] + usum[768 + tid];
        u_part[(size_t)et * M + (size_t)mtile * 256 + tid] = v;
    }
}

// ---------------------------------------------------------------------------
// Kernel 4: masked log-softmax over N=2048 per batch row (4 partial slices).
// ---------------------------------------------------------------------------
__global__ void softmax_k(const float* __restrict__ up, const int* __restrict__ mask,
                          float* __restrict__ out) {
    __shared__ float red[8];
    int b = blockIdx.x, tid = threadIdx.x;
    float l[8];
#pragma unroll
    for (int i = 0; i < 8; ++i) {
        int n = i * 256 + tid;
        float s = up[(size_t)b * Nn + n];
#pragma unroll
        for (int et = 1; et < 4; ++et) s += up[(size_t)et * M + (size_t)b * Nn + n];
        l[i] = s + (mask[b * Nn + n] ? 0.f : -103.278931f);  // ln(2^-149)
    }
    float m = l[0];
#pragma unroll
    for (int i = 1; i < 8; ++i) m = fmaxf(m, l[i]);
#pragma unroll
    for (int o = 32; o >= 1; o >>= 1) m = fmaxf(m, __shfl_xor(m, o, 64));
    if ((tid & 63) == 0) red[tid >> 6] = m;
    __syncthreads();
    m = fmaxf(fmaxf(red[0], red[1]), fmaxf(red[2], red[3]));
    float s = 0.f;
#pragma unroll
    for (int i = 0; i < 8; ++i) s += expf(l[i] - m);
#pragma unroll
    for (int o = 32; o >= 1; o >>= 1) s += __shfl_xor(s, o, 64);
    if ((tid & 63) == 0) red[4 + (tid >> 6)] = s;
    __syncthreads();
    float lse = m + logf(red[4] + red[5] + red[6] + red[7]);
#pragma unroll
    for (int i = 0; i < 8; ++i)
        out[(size_t)b * Nn + i * 256 + tid] = l[i] - lse;
}

// ---------------------------------------------------------------------------
extern "C" void kernel_launch(void* const* d_in, const int* in_sizes, int n_in,
                              void* d_out, int out_size, void* d_ws, size_t ws_size,
                              hipStream_t stream) {
    const float* encoded = (const float*)d_in[0];
    const float* dstate  = (const float*)d_in[1];
    const int*   mask    = (const int*)d_in[2];
    const float* W1      = (const float*)d_in[3];
    const float* W2      = (const float*)d_in[4];
    const float* vt      = (const float*)d_in[5];
    float* out = (float*)d_out;

    // ws layout: u_part (1 MiB) | dec (128 KB) | W1TT (2 MiB)   (~3.2 MB)
    char* ws = (char*)d_ws;
    float*    u_part = (float*)ws;
    float*    dec    = (float*)(ws + (size_t)4 * M * 4);
    _Float16* W1TT   = (_Float16*)(ws + (size_t)4 * M * 4 + (size_t)Bb * Dd * 4);

    static bool attr_done = false;
    if (!attr_done) {
        hipFuncSetAttribute(reinterpret_cast<const void*>(gemm8),
                            hipFuncAttributeMaxDynamicSharedMemorySize, 131072);
        attr_done = true;
    }

    prep_w1<<<512, 256, 0, stream>>>(W1, W1TT);
    dec_kernel<<<dim3(32, 16), 256, 0, stream>>>(dstate, W2, dec);
    gemm8<<<1024, 512, 131072, stream>>>(encoded, W1TT, dec, vt, u_part);
    softmax_k<<<32, 256, 0, stream>>>(u_part, mask, out);
}